// Round 1
// baseline (55173.102 us; speedup 1.0000x reference)
//
#include <hip/hip_runtime.h>

// ---------------- problem dims ----------------
constexpr int BB = 16;       // batch
constexpr int TT = 256;      // seq len
constexpr int IN0 = 512;     // input dim (layer 0)
constexpr int HH = 1024;     // hidden
constexpr int GG = 4096;     // 4*H gates
constexpr int NLAYERS = 8;
constexpr int NWG = 256;     // scan workgroups

// ---------------- ws layout (bytes) ----------------
constexpr size_t XG_OFF    = 0;                         // 4096*4096*4 = 64 MB
constexpr size_t HSA_OFF   = 67108864;                  // 16 MB
constexpr size_t HSB_OFF   = HSA_OFF + 16777216;        // 16 MB
constexpr size_t HGLOB_OFF = HSB_OFF + 16777216;        // 64 KB
constexpr size_t FC1_OFF   = HGLOB_OFF + 65536;         // 32 KB
constexpr size_t FC2_OFF   = FC1_OFF + 32768;           // 16 KB
constexpr size_t BAR_OFF   = FC2_OFF + 16384;           // 2 KB barrier state
// total ~96.2 MB

// scan LDS: Wt 16*1028 + hb 16*1028 + part 1024 + gv 256 floats
constexpr int SCAN_SMEM_FLOATS = 16448 + 16448 + 1024 + 256;
constexpr int SCAN_SMEM_BYTES  = SCAN_SMEM_FLOATS * 4;   // 136,704 B

// ---------------- GEMM: out[m][n] = sum_k X[m][k]*W[n][k] + bih[n]+bhh[n] ----------------
// X: (4096, K) row-major, W: (4096, K) row-major, out: (4096, 4096)
__global__ __launch_bounds__(256) void gemm_xg(const float* __restrict__ X,
                                               const float* __restrict__ W,
                                               const float* __restrict__ bih,
                                               const float* __restrict__ bhh,
                                               float* __restrict__ out, int K)
{
    __shared__ float Xs[64][33];
    __shared__ float Ws[64][33];
    const int tid = threadIdx.x;
    const int tm = tid >> 4, tn = tid & 15;
    const int m0 = blockIdx.y * 64, n0 = blockIdx.x * 64;
    float acc[4][4] = {};

    for (int k0 = 0; k0 < K; k0 += 32) {
#pragma unroll
        for (int i = 0; i < 2; ++i) {
            int f = tid + i * 256;              // 512 float4 loads per operand tile
            int row = f >> 3, c4 = (f & 7) << 2;
            float4 xv = *(const float4*)(X + (size_t)(m0 + row) * K + k0 + c4);
            float4 wv = *(const float4*)(W + (size_t)(n0 + row) * K + k0 + c4);
            Xs[row][c4 + 0] = xv.x; Xs[row][c4 + 1] = xv.y;
            Xs[row][c4 + 2] = xv.z; Xs[row][c4 + 3] = xv.w;
            Ws[row][c4 + 0] = wv.x; Ws[row][c4 + 1] = wv.y;
            Ws[row][c4 + 2] = wv.z; Ws[row][c4 + 3] = wv.w;
        }
        __syncthreads();
#pragma unroll 4
        for (int kk = 0; kk < 32; ++kk) {
            float xr[4], wc[4];
#pragma unroll
            for (int i = 0; i < 4; ++i) xr[i] = Xs[tm * 4 + i][kk];
#pragma unroll
            for (int j = 0; j < 4; ++j) wc[j] = Ws[tn * 4 + j][kk];
#pragma unroll
            for (int i = 0; i < 4; ++i)
#pragma unroll
                for (int j = 0; j < 4; ++j)
                    acc[i][j] = fmaf(xr[i], wc[j], acc[i][j]);
        }
        __syncthreads();
    }

    const int n = n0 + tn * 4;
    const float4 bi = *(const float4*)(bih + n);
    const float4 bh = *(const float4*)(bhh + n);
    const float4 bias = {bi.x + bh.x, bi.y + bh.y, bi.z + bh.z, bi.w + bh.w};
#pragma unroll
    for (int i = 0; i < 4; ++i) {
        float4 o = {acc[i][0] + bias.x, acc[i][1] + bias.y,
                    acc[i][2] + bias.z, acc[i][3] + bias.w};
        *(float4*)(out + (size_t)(m0 + tm * 4 + i) * GG + n) = o;
    }
}

// ---------------- 2-level grid barrier (256 WGs = 16 groups x 16) ----------------
// bar layout (u32): [0..255] 16 group counters at stride 16; [256] root; [272] gen
__device__ __forceinline__ void grid_barrier(unsigned* bar, int wg)
{
    __syncthreads();
    if (threadIdx.x == 0) {
        __threadfence();
        unsigned* gcnt = bar + ((wg >> 4) << 4);
        unsigned* root = bar + 256;
        unsigned* gen  = bar + 272;
        unsigned g = __hip_atomic_load(gen, __ATOMIC_RELAXED, __HIP_MEMORY_SCOPE_AGENT);
        unsigned a = __hip_atomic_fetch_add(gcnt, 1u, __ATOMIC_RELAXED, __HIP_MEMORY_SCOPE_AGENT);
        if (a == 15u) {
            unsigned ra = __hip_atomic_fetch_add(root, 1u, __ATOMIC_RELAXED, __HIP_MEMORY_SCOPE_AGENT);
            if (ra == 15u) {
#pragma unroll
                for (int i = 0; i < 16; ++i)
                    __hip_atomic_store(bar + (i << 4), 0u, __ATOMIC_RELAXED, __HIP_MEMORY_SCOPE_AGENT);
                __hip_atomic_store(root, 0u, __ATOMIC_RELAXED, __HIP_MEMORY_SCOPE_AGENT);
                __hip_atomic_store(gen, g + 1u, __ATOMIC_RELEASE, __HIP_MEMORY_SCOPE_AGENT);
            }
        }
        while (__hip_atomic_load(gen, __ATOMIC_RELAXED, __HIP_MEMORY_SCOPE_AGENT) == g)
            __builtin_amdgcn_s_sleep(2);
        __threadfence();
    }
    __syncthreads();
}

__device__ __forceinline__ float sigf(float x) { return 1.0f / (1.0f + expf(-x)); }

// ---------------- per-layer LSTM scan (persistent, 1 WG/CU) ----------------
// WG w owns h-columns j0=4w..4w+3 -> 16 gate rows: grow = gate*1024 + j0 + jl
__global__ __launch_bounds__(256, 1) void lstm_scan(const float* __restrict__ Whh,
                                                    const float* __restrict__ xg,
                                                    float* __restrict__ hseq,
                                                    float* __restrict__ hglob,
                                                    unsigned* __restrict__ bar)
{
    extern __shared__ float smem[];
    float* Wt   = smem;            // 16 rows x 1028 (pad 4 floats: 2-way banks, 16B aligned)
    float* hb   = smem + 16448;    // 16 rows x 1028
    float* part = smem + 32896;    // [4 waves][16 rows][16 batch]
    float* gv   = smem + 33920;    // [16 rows][16 batch]

    const int tid = threadIdx.x;
    const int wg  = blockIdx.x;
    const int j0  = wg << 2;

    // stage Whh tile once: row r -> global row (r>>2)*1024 + j0 + (r&3)
    float4* Wt4 = (float4*)Wt;
    float4* hb4 = (float4*)hb;
#pragma unroll
    for (int i = 0; i < 16; ++i) {
        int f = tid + (i << 8);
        int r = f >> 8, k4 = f & 255;
        int grow = ((r >> 2) << 10) + j0 + (r & 3);
        Wt4[r * 257 + k4] = *(const float4*)(Whh + ((size_t)grow << 10) + (k4 << 2));
    }

    const int w  = tid >> 6;          // k-quarter per wave
    const int ln = tid & 63;
    const int r2 = ln >> 3, b2 = ln & 7;
    const int rA = r2 << 1, rB = rA + 1, bA = b2 << 1, bB = bA + 1;
    const int r_red = tid >> 4, b_red = tid & 15;
    const int grow_red = ((r_red >> 2) << 10) + j0 + (r_red & 3);
    const int jl = tid >> 4, bg = tid & 15;  // gate-thread ids (tid<64)

    float c_state = 0.0f;
    __syncthreads();

    for (int t = 0; t < TT; ++t) {
        // prefetch this step's xg element early (latency hides under dot)
        float xg_pref = xg[((size_t)(b_red * TT + t)) * GG + grow_red];

        if (t > 0) {   // broadcast h into LDS
#pragma unroll
            for (int i = 0; i < 16; ++i) {
                int f = tid + (i << 8);
                int b = f >> 8, k4 = f & 255;
                hb4[b * 257 + k4] =
                    *(const float4*)(hglob + ((size_t)b << 10) + (k4 << 2));
            }
        }
        __syncthreads();

        float a00 = 0.f, a01 = 0.f, a10 = 0.f, a11 = 0.f;
        if (t > 0) {
            const float4* hA = (const float4*)hb + bA * 257 + (w << 6);
            const float4* hB = (const float4*)hb + bB * 257 + (w << 6);
            const float4* wA = (const float4*)Wt + rA * 257 + (w << 6);
            const float4* wB = (const float4*)Wt + rB * 257 + (w << 6);
#pragma unroll 8
            for (int k = 0; k < 64; ++k) {
                float4 h0 = hA[k], h1 = hB[k], w0 = wA[k], w1 = wB[k];
                a00 += w0.x*h0.x + w0.y*h0.y + w0.z*h0.z + w0.w*h0.w;
                a01 += w0.x*h1.x + w0.y*h1.y + w0.z*h1.z + w0.w*h1.w;
                a10 += w1.x*h0.x + w1.y*h0.y + w1.z*h0.z + w1.w*h0.w;
                a11 += w1.x*h1.x + w1.y*h1.y + w1.z*h1.z + w1.w*h1.w;
            }
        }
        const int pb = (w << 8);
        part[pb + rA * 16 + bA] = a00;
        part[pb + rA * 16 + bB] = a01;
        part[pb + rB * 16 + bA] = a10;
        part[pb + rB * 16 + bB] = a11;
        __syncthreads();

        // reduce k-quarters + add xg (thread tid -> (row=tid>>4, batch=tid&15))
        gv[tid] = part[tid] + part[256 + tid] + part[512 + tid] + part[768 + tid] + xg_pref;
        __syncthreads();

        if (tid < 64) {   // gate math: 4 j x 16 b per WG
            float iv = gv[(jl     ) * 16 + bg];
            float fv = gv[(jl +  4) * 16 + bg];
            float gg = gv[(jl +  8) * 16 + bg];
            float ov = gv[(jl + 12) * 16 + bg];
            c_state = sigf(fv) * c_state + sigf(iv) * tanhf(gg);
            float h = sigf(ov) * tanhf(c_state);
            hglob[((size_t)bg << 10) + j0 + jl] = h;
            hseq[((size_t)(bg * TT + t)) * HH + j0 + jl] = h;
        }
        grid_barrier(bar, wg);
    }
}

// ---------------- FC head ----------------
__global__ void fc_relu(const float* __restrict__ in, const float* __restrict__ w,
                        const float* __restrict__ b, float* __restrict__ out,
                        int N, int K, int do_relu)
{
    int g = blockIdx.x * blockDim.x + threadIdx.x;
    if (g >= BB * N) return;
    int bi = g / N, n = g - bi * N;
    const float* ip = in + (size_t)bi * K;
    const float* wp = w + (size_t)n * K;
    float s = 0.f;
    for (int k = 0; k < K; k += 4) {
        float4 a = *(const float4*)(ip + k);
        float4 q = *(const float4*)(wp + k);
        s += a.x * q.x + a.y * q.y + a.z * q.z + a.w * q.w;
    }
    s += b[n];
    if (do_relu) s = fmaxf(s, 0.f);
    out[g] = s;
}

// ---------------- launch ----------------
extern "C" void kernel_launch(void* const* d_in, const int* in_sizes, int n_in,
                              void* d_out, int out_size, void* d_ws, size_t ws_size,
                              hipStream_t stream)
{
    const float* x    = (const float*)d_in[0];
    const float* Wih0 = (const float*)d_in[1];
    const float* WihR = (const float*)d_in[2];
    const float* Whh  = (const float*)d_in[3];
    const float* bih  = (const float*)d_in[4];
    const float* bhh  = (const float*)d_in[5];
    const float* fc1w = (const float*)d_in[6];
    const float* fc1b = (const float*)d_in[7];
    const float* fc2w = (const float*)d_in[8];
    const float* fc2b = (const float*)d_in[9];
    const float* fc3w = (const float*)d_in[10];
    const float* fc3b = (const float*)d_in[11];
    float* out = (float*)d_out;
    char* ws = (char*)d_ws;

    float* xg    = (float*)(ws + XG_OFF);
    float* hsA   = (float*)(ws + HSA_OFF);
    float* hsB   = (float*)(ws + HSB_OFF);
    float* hglob = (float*)(ws + HGLOB_OFF);
    float* fc1o  = (float*)(ws + FC1_OFF);
    float* fc2o  = (float*)(ws + FC2_OFF);
    unsigned* bar = (unsigned*)(ws + BAR_OFF);

    hipFuncSetAttribute((const void*)lstm_scan,
                        hipFuncAttributeMaxDynamicSharedMemorySize, SCAN_SMEM_BYTES);
    hipMemsetAsync(ws + BAR_OFF, 0, 2048, stream);   // barrier counters + gen = 0

    for (int l = 0; l < NLAYERS; ++l) {
        const float* X  = (l == 0) ? x : ((l & 1) ? hsA : hsB);
        const int K     = (l == 0) ? IN0 : HH;
        const float* Wl = (l == 0) ? Wih0 : (WihR + (size_t)(l - 1) * GG * HH);
        gemm_xg<<<dim3(GG / 64, (BB * TT) / 64), 256, 0, stream>>>(
            X, Wl, bih + (size_t)l * GG, bhh + (size_t)l * GG, xg, K);

        float* hout = (l & 1) ? hsB : hsA;
        const float* whh_l = Whh + (size_t)l * GG * HH;
        void* args[5] = {(void*)&whh_l, (void*)&xg, (void*)&hout,
                         (void*)&hglob, (void*)&bar};
        hipError_t e = hipLaunchCooperativeKernel((void*)lstm_scan, dim3(NWG), dim3(256),
                                                  args, SCAN_SMEM_BYTES, stream);
        if (e != hipSuccess) {
            // fallback: regular launch (1 WG/CU -> co-resident in practice)
            lstm_scan<<<dim3(NWG), dim3(256), SCAN_SMEM_BYTES, stream>>>(
                whh_l, xg, hout, hglob, bar);
        }
    }

    fc_relu<<<32, 256, 0, stream>>>(hglob, fc1w, fc1b, fc1o, 512, 1024, 1);
    fc_relu<<<16, 256, 0, stream>>>(fc1o, fc2w, fc2b, fc2o, 256, 512, 1);
    fc_relu<<<1, 16, 0, stream>>>(fc2o, fc3w, fc3b, out, 1, 256, 0);
}